// Round 18
// baseline (620.150 us; speedup 1.0000x reference)
//
#include <hip/hip_runtime.h>

// ---------- problem constants ----------
#define BB   4096
#define IN_  256
#define NN   128
#define NG   512
#define WS_  131072     // IN*NG
#define PER  131584     // WS_+NG
#define TP   263168     // 2*PER

typedef __attribute__((ext_vector_type(8))) short short8;
typedef __attribute__((ext_vector_type(4))) float f32x4;

__device__ __forceinline__ unsigned short f2bf(float f){
  unsigned u = __float_as_uint(f);
  return (unsigned short)((u + 0x7fffu + ((u >> 16) & 1u)) >> 16);
}

// sum over each 16-lane row via DPP (VALU pipe; validated R9+)
__device__ __forceinline__ float rowred16(float s){
  s += __int_as_float(__builtin_amdgcn_update_dpp(0, __float_as_int(s), 0xB1,  0xF, 0xF, true));
  s += __int_as_float(__builtin_amdgcn_update_dpp(0, __float_as_int(s), 0x4E,  0xF, 0xF, true));
  s += __int_as_float(__builtin_amdgcn_update_dpp(0, __float_as_int(s), 0x124, 0xF, 0xF, true));
  s += __int_as_float(__builtin_amdgcn_update_dpp(0, __float_as_int(s), 0x128, 0xF, 0xF, true));
  return s;
}

// ---------- 1. f32 -> bf16 convert: x only ----------
__global__ void k_convert(const float* __restrict__ x, unsigned short* __restrict__ xb){
  size_t i = ((size_t)blockIdx.x*256 + threadIdx.x)*4;
  float4 v = *(const float4*)(x + i);
  ushort4 o;
  o.x = f2bf(v.x); o.y = f2bf(v.y); o.z = f2bf(v.z); o.w = f2bf(v.w);
  *(ushort4*)(xb + i) = o;
}

// ---------- 2. hypernet MLP + gw matvec (merged) ----------
__global__ __launch_bounds__(512)
void k_gw(const float* __restrict__ ctx,
          const float* __restrict__ h1w, const float* __restrict__ h1b,
          const float* __restrict__ h2w, const float* __restrict__ h2b,
          const float* __restrict__ h3w, const float* __restrict__ h3b,
          unsigned short* __restrict__ Wg_bf, float* __restrict__ bg){
  __shared__ float s1[32];
  __shared__ float hv2[64];
  const int t = threadIdx.x;
  if (t < 32){
    float a = h1b[t];
    #pragma unroll 8
    for (int i = 0; i < 64; ++i) a += ctx[i]*h1w[t*64+i];
    s1[t] = fmaxf(a, 0.f);
  }
  __syncthreads();
  if (t < 64){
    float a = h2b[t];
    #pragma unroll 8
    for (int i = 0; i < 32; ++i) a += s1[i]*h2w[t*32+i];
    hv2[t] = fmaxf(a, 0.f);
  }
  __syncthreads();

  const int r = blockIdx.x*64 + (t >> 3);
  const int q = t & 7;
  const float4* row = (const float4*)(h3w + (size_t)r*64);
  float4 v0 = row[q*2], v1 = row[q*2+1];
  float4 h0 = *(const float4*)(hv2 + q*8), h1 = *(const float4*)(hv2 + q*8 + 4);
  float a = v0.x*h0.x + v0.y*h0.y + v0.z*h0.z + v0.w*h0.w
          + v1.x*h1.x + v1.y*h1.y + v1.z*h1.z + v1.w*h1.w;
  a += __shfl_xor(a, 1);
  a += __shfl_xor(a, 2);
  a += __shfl_xor(a, 4);
  if (q == 0){
    a += h3b[r];
    if (r < WS_)          Wg_bf[r] = f2bf(a);
    else if (r < PER)     bg[r - WS_] = a;
    else if (r < PER+WS_) Wg_bf[WS_ + (r - PER)] = f2bf(a);
    else                  bg[512 + (r - (PER+WS_))] = a;
  }
}

// ---------- 4. gates GEMM: G_T[m][b] = sigmoid(Wg[m]·x[b] + bg[m]) ----------
__global__ __launch_bounds__(512, 1)
void k_gates(const unsigned short* __restrict__ Wg_bf,
             const unsigned short* __restrict__ x_bf,
             const float* __restrict__ bg,
             float* __restrict__ GT){
  __shared__ __align__(16) unsigned short As[128*64];
  __shared__ __align__(16) unsigned short Bs[256*64];
  const int tid  = threadIdx.x;
  const int lane = tid & 63;
  const int wid  = tid >> 6;
  const int wm = wid >> 2, wn = wid & 3;
  const int lrow = lane & 15, lk = lane >> 4;
  const int m0 = blockIdx.x*128;
  const int b0 = blockIdx.y*256;

  f32x4 zero = {0.f,0.f,0.f,0.f};
  f32x4 acc[4][4];
  #pragma unroll
  for (int i=0;i<4;++i)
    #pragma unroll
    for (int j=0;j<4;++j) acc[i][j] = zero;

  for (int kt = 0; kt < 256/64; ++kt){
    __syncthreads();
    #pragma unroll
    for (int i = 0; i < 2; ++i){
      int c = tid + i*512;
      int row = c >> 3, k8 = c & 7;
      uint4 v = *(const uint4*)(Wg_bf + (size_t)(m0+row)*256 + kt*64 + k8*8);
      int idx = (row*64 + k8*8) ^ ((row & 7) << 3);
      *(uint4*)(&As[idx]) = v;
    }
    #pragma unroll
    for (int i = 0; i < 4; ++i){
      int c = tid + i*512;
      int row = c >> 3, k8 = c & 7;
      uint4 v = *(const uint4*)(x_bf + (size_t)(b0+row)*256 + kt*64 + k8*8);
      int idx = (row*64 + k8*8) ^ ((row & 7) << 3);
      *(uint4*)(&Bs[idx]) = v;
    }
    __syncthreads();
    #pragma unroll
    for (int kk = 0; kk < 2; ++kk){
      short8 a[4], b[4];
      #pragma unroll
      for (int fm = 0; fm < 4; ++fm){
        int m = wm*64 + fm*16 + lrow;
        int idx = (m*64 + kk*32 + lk*8) ^ ((m & 7) << 3);
        a[fm] = *(const short8*)(&As[idx]);
      }
      #pragma unroll
      for (int fn = 0; fn < 4; ++fn){
        int r = wn*64 + fn*16 + lrow;
        int idx = (r*64 + kk*32 + lk*8) ^ ((r & 7) << 3);
        b[fn] = *(const short8*)(&Bs[idx]);
      }
      #pragma unroll
      for (int fm = 0; fm < 4; ++fm)
        #pragma unroll
        for (int fn = 0; fn < 4; ++fn)
          acc[fm][fn] = __builtin_amdgcn_mfma_f32_16x16x32_bf16(a[fm], b[fn], acc[fm][fn], 0, 0, 0);
    }
  }
  #pragma unroll
  for (int fm = 0; fm < 4; ++fm){
    float4 bgv = *(const float4*)(bg + m0 + wm*64 + fm*16 + lk*4);
    float bga[4] = {bgv.x, bgv.y, bgv.z, bgv.w};
    #pragma unroll
    for (int reg = 0; reg < 4; ++reg){
      int m = m0 + wm*64 + fm*16 + lk*4 + reg;
      #pragma unroll
      for (int fn = 0; fn < 4; ++fn){
        int b = b0 + wn*64 + fn*16 + lrow;
        float z = acc[fm][fn][reg] + bga[reg];
        GT[(size_t)m*4096 + b] = 1.f/(1.f + __expf(-z));
      }
    }
  }
}

// ---------- 5/6. fused DANN layer (barrier-free, register-dbuf A, 2 blocks/CU) ----------
// No per-phase barriers: LDS holds ONLY resident Wb (64 KB, staged once from
// f32; single __syncthreads). Each wave free-runs its phase chain; A-frags
// global->VGPR DOUBLE-BUFFERED (areg[2][2][2], 32 regs): ALOAD(ph+1) issued
// before ph's MFMAs -> L2 latency (~300cy, x/cur L2-hot) hides under
// MFMA+ds_read. Register total ~122 (areg32 + b16 + acc32 + misc) < 128 ->
// 2 blocks/CU co-reside (64 KB LDS each) = 4 waves/SIMD TLP. Grid 512:
// L0 = 128n x 2khalf x 2bhalf (2048 rows/block); L1 = 128n x 4bquarter
// (1024 rows/block). Wave tile 32x64 (fm2,fn4,kk2=16 MFMA/phase).
// All loads compiler-visible -> compiler inserts exact counted waits.
template<int KIN, int LAYER>
__global__ __launch_bounds__(512, 4)
void k_layer(const unsigned short* __restrict__ Abf,  // (4096, KIN) bf16
             const float* __restrict__ Wf32,          // (32768, KIN) f32
             const float* __restrict__ bb,
             const float* __restrict__ Ws,
             const float* __restrict__ GT,            // 1024 x 4096
             float* __restrict__ partg){              // [4][128][4096] f32
  constexpr int NT   = KIN/64;                   // 4 / 2
  constexpr int SC   = (LAYER==0) ? 128 : 256;   // resident Wb cols
  constexpr int WN   = SC/64;                    // 2 / 4
  constexpr int WM   = 8/WN;                     // 4 / 2
  constexpr int BTR  = WM*32;                    // 128 / 64 rows per bt
  constexpr int BSPL = (LAYER==0) ? 2 : 4;       // batch split
  constexpr int ROWS = 4096/BSPL;                // 2048 / 1024
  constexpr int NBT  = ROWS/BTR;                 // 16 / 16
  constexpr unsigned KTB = SC*64*2;              // bytes per Wb kt-tile
  __shared__ __align__(16) unsigned short lds[SC*64*NT];   // 64 KB exactly

  const int tid  = threadIdx.x;                  // 0..511
  const int lane = tid & 63;
  const int wid  = tid >> 6;                     // 0..7
  const int wn   = wid % WN, wm = wid / WN;
  const int lrow = lane & 15, lk = lane >> 4;

  const int id    = blockIdx.x;                  // 0..511
  const int n     = id >> 2;
  const int khalf = (LAYER==0) ? ((id >> 1) & 1) : 0;
  const int bsub  = (LAYER==0) ? (id & 1) : (id & 3);
  const int abase = bsub * ROWS;
  const int kgrp  = (LAYER==0) ? khalf*2 + wn : wn;
  const int colbase = n*256 + khalf*128;

  f32x4 zero = {0.f,0.f,0.f,0.f};
  f32x4 acc[2][4];
  #pragma unroll
  for (int i=0;i<2;++i)
    #pragma unroll
    for (int jj=0;jj<4;++jj) acc[i][jj] = zero;

  // per-lane A base: rows (abase + wm*32 + fm*16 + lrow), k-chunk lk*8
  const unsigned short* abp = Abf + (size_t)(abase + wm*32 + lrow)*KIN + lk*8;

  // A-frag dbuf loads (global -> VGPR, 4 x dwordx4), static indices (rule 20)
  short8 areg[2][2][2];                          // [buf][kk][fm]
  #define ALOAD(BUF, BT, KT)                                                   \
    _Pragma("unroll")                                                          \
    for (int kk_ = 0; kk_ < 2; ++kk_)                                          \
      _Pragma("unroll")                                                        \
      for (int fm_ = 0; fm_ < 2; ++fm_)                                        \
        areg[BUF][kk_][fm_] = *(const short8*)(abp +                           \
            (size_t)((BT)*BTR + fm_*16)*KIN + (KT)*64 + kk_*32);

  ALOAD(0, 0, 0)                                 // phase-0 A (hides under staging)

  // ---- prologue: Wb f32 -> bf16 swizzled LDS staging ----
  {
    constexpr int CHPR = KIN/8;                  // 16B-pair chunks per Wb row
    #pragma unroll
    for (int half = 0; half < 2; ++half){
      float4 va[4], vb[4];
      #pragma unroll
      for (int j = 0; j < 4; ++j){
        int c = (half*4 + j)*512 + tid;
        int r = c / CHPR, q = c % CHPR;
        const float4* s = (const float4*)(Wf32 + (size_t)(colbase + r)*KIN + q*8);
        va[j] = s[0]; vb[j] = s[1];
      }
      #pragma unroll
      for (int j = 0; j < 4; ++j){
        int c = (half*4 + j)*512 + tid;
        int r = c / CHPR, q = c % CHPR;
        int kt = q >> 3, k8 = q & 7;
        short8 p;
        p[0] = (short)f2bf(va[j].x); p[1] = (short)f2bf(va[j].y);
        p[2] = (short)f2bf(va[j].z); p[3] = (short)f2bf(va[j].w);
        p[4] = (short)f2bf(vb[j].x); p[5] = (short)f2bf(vb[j].y);
        p[6] = (short)f2bf(vb[j].z); p[7] = (short)f2bf(vb[j].w);
        int dst = kt*SC*64 + ((r*64 + k8*8) ^ ((r&7)<<3));
        *(short8*)(&lds[dst]) = p;
      }
    }
  }
  __syncthreads();                               // publish Wb (only barrier)

  // block-constant epilogue params
  float bbv[4], wsv[4];
  #pragma unroll
  for (int fn = 0; fn < 4; ++fn){
    int cloc = khalf*128 + wn*64 + fn*16 + lrow;
    bbv[fn] = bb[n*256 + cloc];
    wsv[fn] = Ws[n*256 + cloc];
  }
  const float* gtrow = GT + (size_t)(LAYER*512 + n*4 + kgrp)*4096 + abase;
  float* prow = partg + (size_t)kgrp*524288 + (size_t)n*4096 + abase;

  unsigned boff[4];
  #pragma unroll
  for (int fn = 0; fn < 4; ++fn){
    int r = wn*64 + fn*16 + lrow;
    boff[fn] = 2u*((unsigned)((r*64 + lk*8) ^ ((r & 7) << 3)));
  }
  const char* ldsc = (const char*)lds;

  #pragma unroll 1
  for (int bt = 0; bt < NBT; ++bt){
    #pragma unroll
    for (int kt = 0; kt < NT; ++kt){
      const int cb = kt & 1;                     // compile-time (kt unrolled)
      const bool epi = (kt == NT-1);

      // issue next phase's A-frags early (hidden under b-reads + MFMAs)
      if (!(epi && bt == NBT-1)){
        int bt2 = epi ? bt+1 : bt;
        int kt2 = epi ? 0    : kt+1;
        if (cb == 0) { ALOAD(1, bt2, kt2) }
        else         { ALOAD(0, bt2, kt2) }
      }

      float4 gv[2];
      if (epi){                                  // gates: load early, used late
        gv[0] = *(const float4*)(gtrow + bt*BTR + wm*32 + lk*4);
        gv[1] = *(const float4*)(gtrow + bt*BTR + wm*32 + 16 + lk*4);
      }

      // b from resident LDS + 16 MFMA on areg[cb]
      #pragma unroll
      for (int kk = 0; kk < 2; ++kk){
        short8 b[4];
        #pragma unroll
        for (int fn = 0; fn < 4; ++fn)
          b[fn] = *(const short8*)(ldsc + (unsigned)kt*KTB
                                   + (boff[fn] ^ (unsigned)(kk*64)));
        #pragma unroll
        for (int fm = 0; fm < 2; ++fm)
          #pragma unroll
          for (int fn = 0; fn < 4; ++fn)
            acc[fm][fn] = __builtin_amdgcn_mfma_f32_16x16x32_bf16(
                areg[cb][kk][fm], b[fn], acc[fm][fn], 0, 0, 0);
      }

      if (epi){
        #pragma unroll
        for (int fm = 0; fm < 2; ++fm){
          float gr[4] = {gv[fm].x, gv[fm].y, gv[fm].z, gv[fm].w};
          float sums[4];
          #pragma unroll
          for (int reg = 0; reg < 4; ++reg){
            float s = 0.f;
            #pragma unroll
            for (int fn = 0; fn < 4; ++fn)
              s += fmaxf(acc[fm][fn][reg] + bbv[fn], 0.f) * wsv[fn];
            sums[reg] = rowred16(s * gr[reg]);
          }
          if (lrow == 0){
            float4 o; o.x = sums[0]; o.y = sums[1]; o.z = sums[2]; o.w = sums[3];
            *(float4*)(prow + bt*BTR + wm*32 + fm*16 + lk*4) = o;
          }
        }
        #pragma unroll
        for (int i2 = 0; i2 < 2; ++i2)
          #pragma unroll
          for (int j2 = 0; j2 < 4; ++j2) acc[i2][j2] = zero;
      }
    }
  }
  #undef ALOAD
}

// ---------- 6.5 partial fold: out[b][n] = sum_k partg[k][n][b] + bs[n] ----------
template<int OUT_BF>
__global__ void k_mid(const float* __restrict__ partg, const float* __restrict__ bsv,
                      unsigned short* __restrict__ obf, float* __restrict__ of32){
  const int n = blockIdx.x;
  const int t = threadIdx.x;
  const float* p = partg + (size_t)n*4096 + t*16;
  const float bsn = bsv[n];
  #pragma unroll
  for (int i = 0; i < 4; ++i){
    float4 s0 = *(const float4*)(p + i*4);
    float4 s1 = *(const float4*)(p + 524288 + i*4);
    float4 s2 = *(const float4*)(p + 2*524288 + i*4);
    float4 s3 = *(const float4*)(p + 3*524288 + i*4);
    float v0 = ((s0.x + s1.x) + s2.x) + s3.x + bsn;
    float v1 = ((s0.y + s1.y) + s2.y) + s3.y + bsn;
    float v2 = ((s0.z + s1.z) + s2.z) + s3.z + bsn;
    float v3 = ((s0.w + s1.w) + s2.w) + s3.w + bsn;
    size_t b = (size_t)t*16 + i*4;
    if (OUT_BF){
      obf[(b+0)*128 + n] = f2bf(v0);
      obf[(b+1)*128 + n] = f2bf(v1);
      obf[(b+2)*128 + n] = f2bf(v2);
      obf[(b+3)*128 + n] = f2bf(v3);
    } else {
      of32[(b+0)*128 + n] = v0;
      of32[(b+1)*128 + n] = v1;
      of32[(b+2)*128 + n] = v2;
      of32[(b+3)*128 + n] = v3;
    }
  }
}

// ---------- 7. final projection: out = cur1 @ Wout.T + bout ----------
__global__ void k_final(const float* __restrict__ out1, const float* __restrict__ Wout,
                        const float* __restrict__ bout, float* __restrict__ out){
  int t = blockIdx.x*256 + threadIdx.x;
  int b = t >> 7, o = t & 127;
  const float4* cr = (const float4*)(out1 + (size_t)b*128);
  const float4* wr = (const float4*)(Wout + (size_t)o*128);
  float a = 0.f;
  #pragma unroll
  for (int i = 0; i < 32; ++i){
    float4 c = cr[i], w = wr[i];
    a += c.x*w.x + c.y*w.y + c.z*w.z + c.w*w.w;
  }
  out[t] = a + bout[o];
}

// ---------- launch ----------
extern "C" void kernel_launch(void* const* d_in, const int* in_sizes, int n_in,
                              void* d_out, int out_size, void* d_ws, size_t ws_size,
                              hipStream_t stream){
  const float* x    = (const float*)d_in[0];
  const float* ctx  = (const float*)d_in[1];
  const float* Wb0  = (const float*)d_in[2];
  const float* bb0  = (const float*)d_in[3];
  const float* Ws0  = (const float*)d_in[4];
  const float* bs0  = (const float*)d_in[5];
  const float* Wb1  = (const float*)d_in[6];
  const float* bb1  = (const float*)d_in[7];
  const float* Ws1  = (const float*)d_in[8];
  const float* bs1  = (const float*)d_in[9];
  const float* Wout = (const float*)d_in[10];
  const float* bout = (const float*)d_in[11];
  const float* h1w  = (const float*)d_in[12];
  const float* h1b  = (const float*)d_in[13];
  const float* h2w  = (const float*)d_in[14];
  const float* h2b  = (const float*)d_in[15];
  const float* h3w  = (const float*)d_in[16];
  const float* h3b  = (const float*)d_in[17];
  float* out = (float*)d_out;

  char* ws = (char*)d_ws;
  size_t o = 0;
  unsigned short* x_bf  = (unsigned short*)(ws + o); o += (size_t)4096*256*2;
  unsigned short* Wg_bf = (unsigned short*)(ws + o); o += (size_t)1024*256*2;
  float* bg     = (float*)(ws + o); o += 1024*4;
  float* GT     = (float*)(ws + o); o += (size_t)1024*4096*4;
  unsigned short* cur_bf = (unsigned short*)(ws + o); o += (size_t)4096*128*2;
  float* out1   = (float*)(ws + o); o += (size_t)4096*128*4;
  float* partg0 = (float*)(ws + o); o += (size_t)4*128*4096*4;   // 8 MB
  float* partg1 = (float*)(ws + o); o += (size_t)4*128*4096*4;   // 8 MB

  k_convert<<<1024, 256, 0, stream>>>(x, x_bf);
  k_gw<<<4112, 512, 0, stream>>>(ctx, h1w, h1b, h2w, h2b, h3w, h3b, Wg_bf, bg);
  k_gates<<<dim3(8, 16), 512, 0, stream>>>(Wg_bf, x_bf, bg, GT);
  k_layer<256, 0><<<512, 512, 0, stream>>>(x_bf, Wb0, bb0, Ws0, GT, partg0);
  k_mid<1><<<128, 256, 0, stream>>>(partg0, bs0, cur_bf, nullptr);
  k_layer<128, 1><<<512, 512, 0, stream>>>(cur_bf, Wb1, bb1, Ws1, GT, partg1);
  k_mid<0><<<128, 256, 0, stream>>>(partg1, bs1, nullptr, out1);
  k_final<<<2048, 256, 0, stream>>>(out1, Wout, bout, out);
}

// Round 19
// 311.889 us; speedup vs baseline: 1.9884x; 1.9884x over previous
//
#include <hip/hip_runtime.h>

// ---------- problem constants ----------
#define BB   4096
#define IN_  256
#define NN   128
#define NG   512
#define WS_  131072     // IN*NG
#define PER  131584     // WS_+NG
#define TP   263168     // 2*PER

typedef __attribute__((ext_vector_type(8))) short short8;
typedef __attribute__((ext_vector_type(4))) float f32x4;

__device__ __forceinline__ unsigned short f2bf(float f){
  unsigned u = __float_as_uint(f);
  return (unsigned short)((u + 0x7fffu + ((u >> 16) & 1u)) >> 16);
}

// sum over each 16-lane row via DPP (VALU pipe; validated R9+)
__device__ __forceinline__ float rowred16(float s){
  s += __int_as_float(__builtin_amdgcn_update_dpp(0, __float_as_int(s), 0xB1,  0xF, 0xF, true));
  s += __int_as_float(__builtin_amdgcn_update_dpp(0, __float_as_int(s), 0x4E,  0xF, 0xF, true));
  s += __int_as_float(__builtin_amdgcn_update_dpp(0, __float_as_int(s), 0x124, 0xF, 0xF, true));
  s += __int_as_float(__builtin_amdgcn_update_dpp(0, __float_as_int(s), 0x128, 0xF, 0xF, true));
  return s;
}

// ---------- 1. f32 -> bf16 convert: x only ----------
__global__ void k_convert(const float* __restrict__ x, unsigned short* __restrict__ xb){
  size_t i = ((size_t)blockIdx.x*256 + threadIdx.x)*4;
  float4 v = *(const float4*)(x + i);
  ushort4 o;
  o.x = f2bf(v.x); o.y = f2bf(v.y); o.z = f2bf(v.z); o.w = f2bf(v.w);
  *(ushort4*)(xb + i) = o;
}

// ---------- 2. hypernet MLP + gw matvec (merged) ----------
__global__ __launch_bounds__(512)
void k_gw(const float* __restrict__ ctx,
          const float* __restrict__ h1w, const float* __restrict__ h1b,
          const float* __restrict__ h2w, const float* __restrict__ h2b,
          const float* __restrict__ h3w, const float* __restrict__ h3b,
          unsigned short* __restrict__ Wg_bf, float* __restrict__ bg){
  __shared__ float s1[32];
  __shared__ float hv2[64];
  const int t = threadIdx.x;
  if (t < 32){
    float a = h1b[t];
    #pragma unroll 8
    for (int i = 0; i < 64; ++i) a += ctx[i]*h1w[t*64+i];
    s1[t] = fmaxf(a, 0.f);
  }
  __syncthreads();
  if (t < 64){
    float a = h2b[t];
    #pragma unroll 8
    for (int i = 0; i < 32; ++i) a += s1[i]*h2w[t*32+i];
    hv2[t] = fmaxf(a, 0.f);
  }
  __syncthreads();

  const int r = blockIdx.x*64 + (t >> 3);
  const int q = t & 7;
  const float4* row = (const float4*)(h3w + (size_t)r*64);
  float4 v0 = row[q*2], v1 = row[q*2+1];
  float4 h0 = *(const float4*)(hv2 + q*8), h1 = *(const float4*)(hv2 + q*8 + 4);
  float a = v0.x*h0.x + v0.y*h0.y + v0.z*h0.z + v0.w*h0.w
          + v1.x*h1.x + v1.y*h1.y + v1.z*h1.z + v1.w*h1.w;
  a += __shfl_xor(a, 1);
  a += __shfl_xor(a, 2);
  a += __shfl_xor(a, 4);
  if (q == 0){
    a += h3b[r];
    if (r < WS_)          Wg_bf[r] = f2bf(a);
    else if (r < PER)     bg[r - WS_] = a;
    else if (r < PER+WS_) Wg_bf[WS_ + (r - PER)] = f2bf(a);
    else                  bg[512 + (r - (PER+WS_))] = a;
  }
}

// ---------- 4. gates GEMM: G_T[m][b] = sigmoid(Wg[m]·x[b] + bg[m]) ----------
__global__ __launch_bounds__(512, 1)
void k_gates(const unsigned short* __restrict__ Wg_bf,
             const unsigned short* __restrict__ x_bf,
             const float* __restrict__ bg,
             float* __restrict__ GT){
  __shared__ __align__(16) unsigned short As[128*64];
  __shared__ __align__(16) unsigned short Bs[256*64];
  const int tid  = threadIdx.x;
  const int lane = tid & 63;
  const int wid  = tid >> 6;
  const int wm = wid >> 2, wn = wid & 3;
  const int lrow = lane & 15, lk = lane >> 4;
  const int m0 = blockIdx.x*128;
  const int b0 = blockIdx.y*256;

  f32x4 zero = {0.f,0.f,0.f,0.f};
  f32x4 acc[4][4];
  #pragma unroll
  for (int i=0;i<4;++i)
    #pragma unroll
    for (int j=0;j<4;++j) acc[i][j] = zero;

  for (int kt = 0; kt < 256/64; ++kt){
    __syncthreads();
    #pragma unroll
    for (int i = 0; i < 2; ++i){
      int c = tid + i*512;
      int row = c >> 3, k8 = c & 7;
      uint4 v = *(const uint4*)(Wg_bf + (size_t)(m0+row)*256 + kt*64 + k8*8);
      int idx = (row*64 + k8*8) ^ ((row & 7) << 3);
      *(uint4*)(&As[idx]) = v;
    }
    #pragma unroll
    for (int i = 0; i < 4; ++i){
      int c = tid + i*512;
      int row = c >> 3, k8 = c & 7;
      uint4 v = *(const uint4*)(x_bf + (size_t)(b0+row)*256 + kt*64 + k8*8);
      int idx = (row*64 + k8*8) ^ ((row & 7) << 3);
      *(uint4*)(&Bs[idx]) = v;
    }
    __syncthreads();
    #pragma unroll
    for (int kk = 0; kk < 2; ++kk){
      short8 a[4], b[4];
      #pragma unroll
      for (int fm = 0; fm < 4; ++fm){
        int m = wm*64 + fm*16 + lrow;
        int idx = (m*64 + kk*32 + lk*8) ^ ((m & 7) << 3);
        a[fm] = *(const short8*)(&As[idx]);
      }
      #pragma unroll
      for (int fn = 0; fn < 4; ++fn){
        int r = wn*64 + fn*16 + lrow;
        int idx = (r*64 + kk*32 + lk*8) ^ ((r & 7) << 3);
        b[fn] = *(const short8*)(&Bs[idx]);
      }
      #pragma unroll
      for (int fm = 0; fm < 4; ++fm)
        #pragma unroll
        for (int fn = 0; fn < 4; ++fn)
          acc[fm][fn] = __builtin_amdgcn_mfma_f32_16x16x32_bf16(a[fm], b[fn], acc[fm][fn], 0, 0, 0);
    }
  }
  #pragma unroll
  for (int fm = 0; fm < 4; ++fm){
    float4 bgv = *(const float4*)(bg + m0 + wm*64 + fm*16 + lk*4);
    float bga[4] = {bgv.x, bgv.y, bgv.z, bgv.w};
    #pragma unroll
    for (int reg = 0; reg < 4; ++reg){
      int m = m0 + wm*64 + fm*16 + lk*4 + reg;
      #pragma unroll
      for (int fn = 0; fn < 4; ++fn){
        int b = b0 + wn*64 + fn*16 + lrow;
        float z = acc[fm][fn][reg] + bga[reg];
        GT[(size_t)m*4096 + b] = 1.f/(1.f + __expf(-z));
      }
    }
  }
}

// ---------- 5/6. fused DANN layer (barrier-free, register-dbuf A) ----------
// IDENTICAL to round 18 except __launch_bounds__(512, 1): empirically the
// 2nd arg only LOWERS the per-wave register budget (512/waves) -- (512,4)
// and (1024,*) pin VGPR=64 and spill; (512,1) allows up to 128.
// This kernel needs ~122 arch regs (areg32 + acc32 + b16 + gv/addr) -> fits.
// LDS = resident Wb only, exactly 64 KB -> with <=128 regs the HW can still
// co-schedule 2 blocks/CU (4 waves/SIMD TLP), no barriers in main loop.
template<int KIN, int LAYER>
__global__ __launch_bounds__(512, 1)
void k_layer(const unsigned short* __restrict__ Abf,  // (4096, KIN) bf16
             const float* __restrict__ Wf32,          // (32768, KIN) f32
             const float* __restrict__ bb,
             const float* __restrict__ Ws,
             const float* __restrict__ GT,            // 1024 x 4096
             float* __restrict__ partg){              // [4][128][4096] f32
  constexpr int NT   = KIN/64;                   // 4 / 2
  constexpr int SC   = (LAYER==0) ? 128 : 256;   // resident Wb cols
  constexpr int WN   = SC/64;                    // 2 / 4
  constexpr int WM   = 8/WN;                     // 4 / 2
  constexpr int BTR  = WM*32;                    // 128 / 64 rows per bt
  constexpr int BSPL = (LAYER==0) ? 2 : 4;       // batch split
  constexpr int ROWS = 4096/BSPL;                // 2048 / 1024
  constexpr int NBT  = ROWS/BTR;                 // 16 / 16
  constexpr unsigned KTB = SC*64*2;              // bytes per Wb kt-tile
  __shared__ __align__(16) unsigned short lds[SC*64*NT];   // 64 KB exactly

  const int tid  = threadIdx.x;                  // 0..511
  const int lane = tid & 63;
  const int wid  = tid >> 6;                     // 0..7
  const int wn   = wid % WN, wm = wid / WN;
  const int lrow = lane & 15, lk = lane >> 4;

  const int id    = blockIdx.x;                  // 0..511
  const int n     = id >> 2;
  const int khalf = (LAYER==0) ? ((id >> 1) & 1) : 0;
  const int bsub  = (LAYER==0) ? (id & 1) : (id & 3);
  const int abase = bsub * ROWS;
  const int kgrp  = (LAYER==0) ? khalf*2 + wn : wn;
  const int colbase = n*256 + khalf*128;

  f32x4 zero = {0.f,0.f,0.f,0.f};
  f32x4 acc[2][4];
  #pragma unroll
  for (int i=0;i<2;++i)
    #pragma unroll
    for (int jj=0;jj<4;++jj) acc[i][jj] = zero;

  // per-lane A base: rows (abase + wm*32 + fm*16 + lrow), k-chunk lk*8
  const unsigned short* abp = Abf + (size_t)(abase + wm*32 + lrow)*KIN + lk*8;

  // A-frag dbuf loads (global -> VGPR, 4 x dwordx4), static indices (rule 20)
  short8 areg[2][2][2];                          // [buf][kk][fm]
  #define ALOAD(BUF, BT, KT)                                                   \
    _Pragma("unroll")                                                          \
    for (int kk_ = 0; kk_ < 2; ++kk_)                                          \
      _Pragma("unroll")                                                        \
      for (int fm_ = 0; fm_ < 2; ++fm_)                                        \
        areg[BUF][kk_][fm_] = *(const short8*)(abp +                           \
            (size_t)((BT)*BTR + fm_*16)*KIN + (KT)*64 + kk_*32);

  ALOAD(0, 0, 0)                                 // phase-0 A (hides under staging)

  // ---- prologue: Wb f32 -> bf16 swizzled LDS staging ----
  {
    constexpr int CHPR = KIN/8;                  // 16B-pair chunks per Wb row
    #pragma unroll
    for (int half = 0; half < 2; ++half){
      float4 va[4], vb[4];
      #pragma unroll
      for (int j = 0; j < 4; ++j){
        int c = (half*4 + j)*512 + tid;
        int r = c / CHPR, q = c % CHPR;
        const float4* s = (const float4*)(Wf32 + (size_t)(colbase + r)*KIN + q*8);
        va[j] = s[0]; vb[j] = s[1];
      }
      #pragma unroll
      for (int j = 0; j < 4; ++j){
        int c = (half*4 + j)*512 + tid;
        int r = c / CHPR, q = c % CHPR;
        int kt = q >> 3, k8 = q & 7;
        short8 p;
        p[0] = (short)f2bf(va[j].x); p[1] = (short)f2bf(va[j].y);
        p[2] = (short)f2bf(va[j].z); p[3] = (short)f2bf(va[j].w);
        p[4] = (short)f2bf(vb[j].x); p[5] = (short)f2bf(vb[j].y);
        p[6] = (short)f2bf(vb[j].z); p[7] = (short)f2bf(vb[j].w);
        int dst = kt*SC*64 + ((r*64 + k8*8) ^ ((r&7)<<3));
        *(short8*)(&lds[dst]) = p;
      }
    }
  }
  __syncthreads();                               // publish Wb (only barrier)

  // block-constant epilogue params
  float bbv[4], wsv[4];
  #pragma unroll
  for (int fn = 0; fn < 4; ++fn){
    int cloc = khalf*128 + wn*64 + fn*16 + lrow;
    bbv[fn] = bb[n*256 + cloc];
    wsv[fn] = Ws[n*256 + cloc];
  }
  const float* gtrow = GT + (size_t)(LAYER*512 + n*4 + kgrp)*4096 + abase;
  float* prow = partg + (size_t)kgrp*524288 + (size_t)n*4096 + abase;

  unsigned boff[4];
  #pragma unroll
  for (int fn = 0; fn < 4; ++fn){
    int r = wn*64 + fn*16 + lrow;
    boff[fn] = 2u*((unsigned)((r*64 + lk*8) ^ ((r & 7) << 3)));
  }
  const char* ldsc = (const char*)lds;

  #pragma unroll 1
  for (int bt = 0; bt < NBT; ++bt){
    #pragma unroll
    for (int kt = 0; kt < NT; ++kt){
      const int cb = kt & 1;                     // compile-time (kt unrolled)
      const bool epi = (kt == NT-1);

      // issue next phase's A-frags early (hidden under b-reads + MFMAs)
      if (!(epi && bt == NBT-1)){
        int bt2 = epi ? bt+1 : bt;
        int kt2 = epi ? 0    : kt+1;
        if (cb == 0) { ALOAD(1, bt2, kt2) }
        else         { ALOAD(0, bt2, kt2) }
      }

      float4 gv[2];
      if (epi){                                  // gates: load early, used late
        gv[0] = *(const float4*)(gtrow + bt*BTR + wm*32 + lk*4);
        gv[1] = *(const float4*)(gtrow + bt*BTR + wm*32 + 16 + lk*4);
      }

      // b from resident LDS + 16 MFMA on areg[cb]
      #pragma unroll
      for (int kk = 0; kk < 2; ++kk){
        short8 b[4];
        #pragma unroll
        for (int fn = 0; fn < 4; ++fn)
          b[fn] = *(const short8*)(ldsc + (unsigned)kt*KTB
                                   + (boff[fn] ^ (unsigned)(kk*64)));
        #pragma unroll
        for (int fm = 0; fm < 2; ++fm)
          #pragma unroll
          for (int fn = 0; fn < 4; ++fn)
            acc[fm][fn] = __builtin_amdgcn_mfma_f32_16x16x32_bf16(
                areg[cb][kk][fm], b[fn], acc[fm][fn], 0, 0, 0);
      }

      if (epi){
        #pragma unroll
        for (int fm = 0; fm < 2; ++fm){
          float gr[4] = {gv[fm].x, gv[fm].y, gv[fm].z, gv[fm].w};
          float sums[4];
          #pragma unroll
          for (int reg = 0; reg < 4; ++reg){
            float s = 0.f;
            #pragma unroll
            for (int fn = 0; fn < 4; ++fn)
              s += fmaxf(acc[fm][fn][reg] + bbv[fn], 0.f) * wsv[fn];
            sums[reg] = rowred16(s * gr[reg]);
          }
          if (lrow == 0){
            float4 o; o.x = sums[0]; o.y = sums[1]; o.z = sums[2]; o.w = sums[3];
            *(float4*)(prow + bt*BTR + wm*32 + fm*16 + lk*4) = o;
          }
        }
        #pragma unroll
        for (int i2 = 0; i2 < 2; ++i2)
          #pragma unroll
          for (int j2 = 0; j2 < 4; ++j2) acc[i2][j2] = zero;
      }
    }
  }
  #undef ALOAD
}

// ---------- 6.5 partial fold: out[b][n] = sum_k partg[k][n][b] + bs[n] ----------
template<int OUT_BF>
__global__ void k_mid(const float* __restrict__ partg, const float* __restrict__ bsv,
                      unsigned short* __restrict__ obf, float* __restrict__ of32){
  const int n = blockIdx.x;
  const int t = threadIdx.x;
  const float* p = partg + (size_t)n*4096 + t*16;
  const float bsn = bsv[n];
  #pragma unroll
  for (int i = 0; i < 4; ++i){
    float4 s0 = *(const float4*)(p + i*4);
    float4 s1 = *(const float4*)(p + 524288 + i*4);
    float4 s2 = *(const float4*)(p + 2*524288 + i*4);
    float4 s3 = *(const float4*)(p + 3*524288 + i*4);
    float v0 = ((s0.x + s1.x) + s2.x) + s3.x + bsn;
    float v1 = ((s0.y + s1.y) + s2.y) + s3.y + bsn;
    float v2 = ((s0.z + s1.z) + s2.z) + s3.z + bsn;
    float v3 = ((s0.w + s1.w) + s2.w) + s3.w + bsn;
    size_t b = (size_t)t*16 + i*4;
    if (OUT_BF){
      obf[(b+0)*128 + n] = f2bf(v0);
      obf[(b+1)*128 + n] = f2bf(v1);
      obf[(b+2)*128 + n] = f2bf(v2);
      obf[(b+3)*128 + n] = f2bf(v3);
    } else {
      of32[(b+0)*128 + n] = v0;
      of32[(b+1)*128 + n] = v1;
      of32[(b+2)*128 + n] = v2;
      of32[(b+3)*128 + n] = v3;
    }
  }
}

// ---------- 7. final projection: out = cur1 @ Wout.T + bout ----------
__global__ void k_final(const float* __restrict__ out1, const float* __restrict__ Wout,
                        const float* __restrict__ bout, float* __restrict__ out){
  int t = blockIdx.x*256 + threadIdx.x;
  int b = t >> 7, o = t & 127;
  const float4* cr = (const float4*)(out1 + (size_t)b*128);
  const float4* wr = (const float4*)(Wout + (size_t)o*128);
  float a = 0.f;
  #pragma unroll
  for (int i = 0; i < 32; ++i){
    float4 c = cr[i], w = wr[i];
    a += c.x*w.x + c.y*w.y + c.z*w.z + c.w*w.w;
  }
  out[t] = a + bout[o];
}

// ---------- launch ----------
extern "C" void kernel_launch(void* const* d_in, const int* in_sizes, int n_in,
                              void* d_out, int out_size, void* d_ws, size_t ws_size,
                              hipStream_t stream){
  const float* x    = (const float*)d_in[0];
  const float* ctx  = (const float*)d_in[1];
  const float* Wb0  = (const float*)d_in[2];
  const float* bb0  = (const float*)d_in[3];
  const float* Ws0  = (const float*)d_in[4];
  const float* bs0  = (const float*)d_in[5];
  const float* Wb1  = (const float*)d_in[6];
  const float* bb1  = (const float*)d_in[7];
  const float* Ws1  = (const float*)d_in[8];
  const float* bs1  = (const float*)d_in[9];
  const float* Wout = (const float*)d_in[10];
  const float* bout = (const float*)d_in[11];
  const float* h1w  = (const float*)d_in[12];
  const float* h1b  = (const float*)d_in[13];
  const float* h2w  = (const float*)d_in[14];
  const float* h2b  = (const float*)d_in[15];
  const float* h3w  = (const float*)d_in[16];
  const float* h3b  = (const float*)d_in[17];
  float* out = (float*)d_out;

  char* ws = (char*)d_ws;
  size_t o = 0;
  unsigned short* x_bf  = (unsigned short*)(ws + o); o += (size_t)4096*256*2;
  unsigned short* Wg_bf = (unsigned short*)(ws + o); o += (size_t)1024*256*2;
  float* bg     = (float*)(ws + o); o += 1024*4;
  float* GT     = (float*)(ws + o); o += (size_t)1024*4096*4;
  unsigned short* cur_bf = (unsigned short*)(ws + o); o += (size_t)4096*128*2;
  float* out1   = (float*)(ws + o); o += (size_t)4096*128*4;
  float* partg0 = (float*)(ws + o); o += (size_t)4*128*4096*4;   // 8 MB
  float* partg1 = (float*)(ws + o); o += (size_t)4*128*4096*4;   // 8 MB

  k_convert<<<1024, 256, 0, stream>>>(x, x_bf);
  k_gw<<<4112, 512, 0, stream>>>(ctx, h1w, h1b, h2w, h2b, h3w, h3b, Wg_bf, bg);
  k_gates<<<dim3(8, 16), 512, 0, stream>>>(Wg_bf, x_bf, bg, GT);
  k_layer<256, 0><<<512, 512, 0, stream>>>(x_bf, Wb0, bb0, Ws0, GT, partg0);
  k_mid<1><<<128, 256, 0, stream>>>(partg0, bs0, cur_bf, nullptr);
  k_layer<128, 1><<<512, 512, 0, stream>>>(cur_bf, Wb1, bb1, Ws1, GT, partg1);
  k_mid<0><<<128, 256, 0, stream>>>(partg1, bs1, nullptr, out1);
  k_final<<<2048, 256, 0, stream>>>(out1, Wout, bout, out);
}